// Round 10
// baseline (2407.910 us; speedup 1.0000x reference)
//
#include <hip/hip_runtime.h>
#include <hip/hip_bf16.h>
#include <math.h>

#define B_  2
#define T_  2048
#define D_  1024
#define H_  16
#define TOK (B_*T_)   // 4096

typedef __attribute__((ext_vector_type(8)))  short bf16x8;
typedef __attribute__((ext_vector_type(4)))  float f32x4;
typedef __attribute__((ext_vector_type(16))) float f32x16;

static __device__ __forceinline__ float bf2f(short u) {
    union { unsigned int i; float f; } c;
    c.i = ((unsigned int)(unsigned short)u) << 16;
    return c.f;
}
static __device__ __forceinline__ short f2bf(float f) {
    union { float f; unsigned int i; } c; c.f = f;
    unsigned int r = c.i + 0x7fff + ((c.i >> 16) & 1);   // RTNE
    return (short)(r >> 16);
}
// v_cvt_pk_bf16_f32: packs {lo, hi} into one u32 (no builtin on gfx950)
static __device__ __forceinline__ unsigned cvtpk(float lo, float hi2) {
    unsigned r;
    asm("v_cvt_pk_bf16_f32 %0, %1, %2" : "=v"(r) : "v"(lo), "v"(hi2));
    return r;
}

// ---------------------------------------------------------------------------
// fused f32->bf16 cast for x + 4 weights, plus RoPE cos/sin table.
// ---------------------------------------------------------------------------
__global__ __launch_bounds__(256) void cast_table(
    const float* __restrict__ x,  const float* __restrict__ wq,
    const float* __restrict__ wk, const float* __restrict__ wv,
    const float* __restrict__ wo,
    short* __restrict__ xb,  short* __restrict__ wqb,
    short* __restrict__ wkb, short* __restrict__ wvb,
    short* __restrict__ wob, float2* __restrict__ tab)
{
    const int bid = blockIdx.x;
    if (bid >= 4096) {                       // RoPE table: T_*32 entries
        int idx = (bid - 4096) * 256 + threadIdx.x;
        int t = idx >> 5, i = idx & 31;
        float freq = __powf(10000.f, -(float)i * (1.0f / 32.0f));
        float s, c;
        sincosf((float)t * freq, &s, &c);
        tab[idx] = make_float2(c, s);
        return;
    }
    int i = bid * 256 + threadIdx.x;         // 0 .. 1048575
    const float* src; short* dst; int off;
    if (i < 524288) { src = x; dst = xb; off = i; }
    else {
        int j = i - 524288;
        int wsel = j >> 17;  off = j & 131071;
        src = wsel == 0 ? wq : wsel == 1 ? wk : wsel == 2 ? wv : wo;
        dst = wsel == 0 ? wqb : wsel == 1 ? wkb : wsel == 2 ? wvb : wob;
    }
    const float4* p = reinterpret_cast<const float4*>(src);
    float4 a = p[2*off], b = p[2*off+1];
    bf16x8 o;
    o[0] = f2bf(a.x); o[1] = f2bf(a.y); o[2] = f2bf(a.z); o[3] = f2bf(a.w);
    o[4] = f2bf(b.x); o[5] = f2bf(b.y); o[6] = f2bf(b.z); o[7] = f2bf(b.w);
    reinterpret_cast<bf16x8*>(dst)[off] = o;
}

// ---------------------------------------------------------------------------
// Fused RoPE for Q and K.  Q pre-scaled by 0.125*log2(e)  (exp2-domain softmax).
// ---------------------------------------------------------------------------
__global__ __launch_bounds__(256) void rope_apply2(short* __restrict__ Q,
                                                   short* __restrict__ K,
                                                   const float2* __restrict__ tab)
{
    int g = blockIdx.x * 256 + threadIdx.x;
    short* X;
    float sc;
    int q;
    if (g < 524288) { X = Q; sc = 0.18033688011112042f; q = g; }
    else            { X = K; sc = 1.0f;                 q = g - 524288; }
    int p0 = q << 2;
    int tt = (p0 >> 9) & (T_ - 1);
    int i0 = p0 & 31;
    int4 v = reinterpret_cast<int4*>(X)[q];
    int out[4]; int vv[4] = {v.x, v.y, v.z, v.w};
#pragma unroll
    for (int j = 0; j < 4; ++j) {
        float2 cs = tab[tt * 32 + i0 + j];
        float re = bf2f((short)(vv[j] & 0xffff));
        float im = bf2f((short)(((unsigned int)vv[j]) >> 16));
        float nr = (re * cs.x - im * cs.y) * sc;
        float ni = (re * cs.y + im * cs.x) * sc;
        out[j] = (int)(unsigned short)f2bf(nr) |
                 ((int)(unsigned short)f2bf(ni) << 16);
    }
    reinterpret_cast<int4*>(X)[q] = make_int4(out[0], out[1], out[2], out[3]);
}

// ---------------------------------------------------------------------------
// bf16 MFMA GEMM (m97 structure).  sel==2 with BF16OUT writes V TRANSPOSED.
// ---------------------------------------------------------------------------
template<int BF16OUT>
__global__ __launch_bounds__(256) void gemm_abt_mfma(
    const short* __restrict__ A,
    const short* __restrict__ B0, const short* __restrict__ B1, const short* __restrict__ B2,
    short* __restrict__ Ob0, short* __restrict__ Ob1, short* __restrict__ Ob2,
    float* __restrict__ Of0, int K)
{
    __shared__ short As[128 * 32];
    __shared__ short Bs[128 * 32];
    __shared__ short Tb[128 * 136];          // transpose buffer (V path only)
    const int sel = blockIdx.x >> 3;
    const int bn  = (blockIdx.x & 7) << 7;
    const int bm  = blockIdx.y << 7;
    const short* Bm = sel == 0 ? B0 : (sel == 1 ? B1 : B2);
    short* Obp      = sel == 0 ? Ob0 : (sel == 1 ? Ob1 : Ob2);
    const int tid  = threadIdx.x;
    const int wv   = tid >> 6, lane = tid & 63;
    const int wr   = wv >> 1,  wc   = wv & 1;
    const int fr   = lane & 15, fg  = lane >> 4;
    const int srow  = lane >> 2;
    const int skoff = (lane & 3) << 3;
    f32x4 acc[4][4] = {};

    for (int k0 = 0; k0 < K; k0 += 32) {
        __syncthreads();
#pragma unroll
        for (int it = 0; it < 2; ++it) {
            const int c = wv * 2 + it;
            const int r = 16 * c + srow;
            __builtin_amdgcn_global_load_lds(
                (const __attribute__((address_space(1))) unsigned int*)
                    (A + (size_t)(bm + r) * K + k0 + skoff),
                (__attribute__((address_space(3))) unsigned int*)(As + c * 512),
                16, 0, 0);
            __builtin_amdgcn_global_load_lds(
                (const __attribute__((address_space(1))) unsigned int*)
                    (Bm + (size_t)(bn + r) * K + k0 + skoff),
                (__attribute__((address_space(3))) unsigned int*)(Bs + c * 512),
                16, 0, 0);
        }
        __syncthreads();
        bf16x8 af[4], bfr[4];
#pragma unroll
        for (int m = 0; m < 4; ++m)
            af[m] = *(const bf16x8*)(As + (wr * 64 + m * 16 + fr) * 32 + fg * 8);
#pragma unroll
        for (int n = 0; n < 4; ++n)
            bfr[n] = *(const bf16x8*)(Bs + (wc * 64 + n * 16 + fr) * 32 + fg * 8);
#pragma unroll
        for (int m = 0; m < 4; ++m)
#pragma unroll
            for (int n = 0; n < 4; ++n)
                acc[m][n] = __builtin_amdgcn_mfma_f32_16x16x32_bf16(
                                af[m], bfr[n], acc[m][n], 0, 0, 0);
    }

    if (BF16OUT && sel == 2) {
#pragma unroll
        for (int m = 0; m < 4; ++m)
#pragma unroll
            for (int n = 0; n < 4; ++n) {
                const int dl = wc * 64 + n * 16 + fr;
                const int tk = wr * 64 + m * 16 + fg * 4;
                unsigned lo  = cvtpk(acc[m][n][0], acc[m][n][1]);
                unsigned hi2 = cvtpk(acc[m][n][2], acc[m][n][3]);
                *(unsigned*)(Tb + dl * 136 + tk)     = lo;
                *(unsigned*)(Tb + dl * 136 + tk + 2) = hi2;
            }
        __syncthreads();
        const int bb = bm >> 11;
#pragma unroll
        for (int it = 0; it < 8; ++it) {
            const int c  = it * 256 + tid;
            const int dl = c >> 4;
            const int off = (c & 15) << 3;
            bf16x8 v = *(const bf16x8*)(Tb + dl * 136 + off);
            *(bf16x8*)(Obp + (size_t)(bb * 1024 + bn + dl) * 2048
                             + (bm & 2047) + off) = v;
        }
        return;
    }

    const int row0 = bm + wr * 64 + fg * 4;
    const int col0 = bn + wc * 64 + fr;
#pragma unroll
    for (int m = 0; m < 4; ++m)
#pragma unroll
        for (int n = 0; n < 4; ++n)
#pragma unroll
            for (int j = 0; j < 4; ++j) {
                const size_t idx = (size_t)(row0 + m * 16 + j) * 1024 + col0 + n * 16;
                if (BF16OUT) Obp[idx] = f2bf(acc[m][n][j]);
                else         Of0[idx] = acc[m][n][j];
            }
}

// ---------------------------------------------------------------------------
// Flash attention v6: kv-split across 4 waves + LDS combine.
// Block = one 32-q-row tile of one (b,h); wave w handles kv tiles t≡w (mod 4).
// 8192 waves total -> 32 waves/CU resident (VGPR<=64, LDS 17.4KB).
// bid->rank map places 4 complementary rank pairs (nt_r + nt_{63-r} = 33) on
// each CU under round-robin dispatch => per-CU work ~exactly equal.
// Combine: m*,l* from per-wave (m,l) in LDS; O via 2-stage LDS tree sum (f32);
// wave 0 runs the proven v5 epilogue; 256-thread coalesced final store.
// ---------------------------------------------------------------------------
__global__ __launch_bounds__(256, 8) void attn_v6(
    const short* __restrict__ Qb, const short* __restrict__ Kb,
    const short* __restrict__ Vt, short* __restrict__ Ob)
{
    __shared__ float Of2[2][2048];           // 16 KB combine buffers
    __shared__ float Ml[4][2][32];           // per-wave m,l

    const int tid  = threadIdx.x;
    const int w    = tid >> 6, lane = tid & 63;
    const int ql   = lane & 31, hi = lane >> 5;

    // balanced bid -> (bh, rank): each CU's round-robin set = complementary pairs
    const int bid = (int)blockIdx.x;         // 0..2047
    const int u  = bid >> 8;                 // 0..7
    const int v  = bid & 255;
    const int bh = v & 31;
    const int r0 = (v >> 5) & 7;
    const int rank = (u & 1) ? (63 - ((u >> 1) << 3) - r0)
                             : (((u >> 1) << 3) + r0);
    const int b   = bh >> 4, h = bh & 15;
    const int q0  = rank * 32;
    const int q_glob = q0 + ql;
    const int nt  = (rank >> 1) + 1;

    // Q fragments (B-operand): lane needs Q[q_glob][16*ds + 8*hi + e]
    const short* qp = Qb + (size_t)(b * T_ + q_glob) * D_ + h * 64 + hi * 8;
    bf16x8 qf[4];
#pragma unroll
    for (int ds = 0; ds < 4; ++ds)
        qf[ds] = *(const bf16x8*)(qp + 16 * ds);

    float m_run = -3e38f, l_run = 0.f;
    f32x16 accO0, accO1;
#pragma unroll
    for (int r = 0; r < 16; ++r) { accO0[r] = 0.f; accO1[r] = 0.f; }

    const short* kbase = Kb + (size_t)(b * T_) * D_ + h * 64 + hi * 8;
    const short* vbase = Vt + (size_t)(bh * 64) * 2048 + hi * 8;

    for (int t = w; t < nt; t += 4) {        // interleaved kv chunks
        const int K0 = t << 6;
        const bool diag  = (K0 + 63 > q0);
        const bool useHi = (K0 + 32 <= q0 + 31);

        // ---- K fragment loads (16B per lane) ----
        const short* kp = kbase + (size_t)K0 * D_;
        bf16x8 kf0[4], kf1[4];
#pragma unroll
        for (int ds = 0; ds < 4; ++ds)
            kf0[ds] = *(const bf16x8*)(kp + (size_t)ql * D_ + 16 * ds);
        if (useHi) {
#pragma unroll
            for (int ds = 0; ds < 4; ++ds)
                kf1[ds] = *(const bf16x8*)(kp + (size_t)(32 + ql) * D_ + 16 * ds);
        }

        // ---- S^T = K Q ----
        f32x16 s0, s1;
#pragma unroll
        for (int r = 0; r < 16; ++r) { s0[r] = 0.f; s1[r] = 0.f; }
#pragma unroll
        for (int ds = 0; ds < 4; ++ds)
            s0 = __builtin_amdgcn_mfma_f32_32x32x16_bf16(kf0[ds], qf[ds], s0, 0, 0, 0);
        if (useHi) {
#pragma unroll
            for (int ds = 0; ds < 4; ++ds)
                s1 = __builtin_amdgcn_mfma_f32_32x32x16_bf16(kf1[ds], qf[ds], s1, 0, 0, 0);
        }

        // ---- causal mask ----
        if (diag) {
            const int qrel = q_glob - K0;
#pragma unroll
            for (int r = 0; r < 16; ++r) {
                const int kv0 = 4 * hi + (r & 3) + 8 * (r >> 2);
                s0[r] = (kv0 <= qrel) ? s0[r] : -3e38f;
            }
            if (useHi) {
#pragma unroll
                for (int r = 0; r < 16; ++r) {
                    const int kv0 = 4 * hi + (r & 3) + 8 * (r >> 2);
                    s1[r] = (kv0 + 32 <= qrel) ? s1[r] : -3e38f;
                }
            }
        }

        // ---- online softmax (exp2 domain, defer-max) ----
        float mloc = s0[0];
#pragma unroll
        for (int r = 1; r < 16; ++r) mloc = fmaxf(mloc, s0[r]);
        if (useHi) {
#pragma unroll
            for (int r = 0; r < 16; ++r) mloc = fmaxf(mloc, s1[r]);
        }
        mloc = fmaxf(mloc, __shfl_xor(mloc, 32));
        if (!__all(mloc <= m_run + 11.5f)) {
            const float mnew = fmaxf(m_run, mloc);
            const float corr = exp2f(m_run - mnew);
            m_run = mnew;
            l_run *= corr;
#pragma unroll
            for (int r = 0; r < 16; ++r) { accO0[r] *= corr; accO1[r] *= corr; }
        }
        float lsum = 0.f;
#pragma unroll
        for (int r = 0; r < 16; ++r) { s0[r] = exp2f(s0[r] - m_run); lsum += s0[r]; }
        if (useHi) {
#pragma unroll
            for (int r = 0; r < 16; ++r) { s1[r] = exp2f(s1[r] - m_run); lsum += s1[r]; }
        }
        lsum += __shfl_xor(lsum, 32);
        l_run += lsum;

        // ---- pack P to bf16 ----
        unsigned W[8][2];
#pragma unroll
        for (int q4 = 0; q4 < 4; ++q4) {
            W[q4][0] = cvtpk(s0[4*q4+0], s0[4*q4+1]);
            W[q4][1] = cvtpk(s0[4*q4+2], s0[4*q4+3]);
        }
        if (useHi) {
#pragma unroll
            for (int q4 = 0; q4 < 4; ++q4) {
                W[q4 + 4][0] = cvtpk(s1[4*q4+0], s1[4*q4+1]);
                W[q4 + 4][1] = cvtpk(s1[4*q4+2], s1[4*q4+3]);
            }
        }

        // ---- PV: O^T += V^T P^T ----
#pragma unroll
        for (int sl = 0; sl < 4; ++sl) {
            if (sl < 2 || useHi) {
                const int qe = 2 * sl, qo = qe + 1;
                unsigned srcA = hi ? W[qe][0] : W[qo][0];
                unsigned srcB = hi ? W[qe][1] : W[qo][1];
                unsigned xA = (unsigned)__shfl_xor((int)srcA, 32);
                unsigned xB = (unsigned)__shfl_xor((int)srcB, 32);
                union { unsigned u[4]; bf16x8 v; } pu;
                pu.u[0] = hi ? xA : W[qe][0];
                pu.u[1] = hi ? xB : W[qe][1];
                pu.u[2] = hi ? W[qo][0] : xA;
                pu.u[3] = hi ? W[qo][1] : xB;
                bf16x8 vf0 = *(const bf16x8*)(vbase + (size_t)ql * 2048        + K0 + 16 * sl);
                bf16x8 vf1 = *(const bf16x8*)(vbase + (size_t)(32 + ql) * 2048 + K0 + 16 * sl);
                accO0 = __builtin_amdgcn_mfma_f32_32x32x16_bf16(vf0, pu.v, accO0, 0, 0, 0);
                accO1 = __builtin_amdgcn_mfma_f32_32x32x16_bf16(vf1, pu.v, accO1, 0, 0, 0);
            }
        }
    }

    // ================= cross-wave combine =================
    if (hi == 0) { Ml[w][0][ql] = m_run; Ml[w][1][ql] = l_run; }
    __syncthreads();
    const float mstar = fmaxf(fmaxf(Ml[0][0][ql], Ml[1][0][ql]),
                              fmaxf(Ml[2][0][ql], Ml[3][0][ql]));
    const float lstar = exp2f(Ml[0][0][ql] - mstar) * Ml[0][1][ql]
                      + exp2f(Ml[1][0][ql] - mstar) * Ml[1][1][ql]
                      + exp2f(Ml[2][0][ql] - mstar) * Ml[2][1][ql]
                      + exp2f(Ml[3][0][ql] - mstar) * Ml[3][1][ql];
    {
        const float wgt = exp2f(m_run - mstar);   // 0 for empty chunks
#pragma unroll
        for (int r = 0; r < 16; ++r) { accO0[r] *= wgt; accO1[r] *= wgt; }
    }
    // stage A: waves 1,3 publish; waves 0,2 accumulate
    if (w & 1) {
        float* dst = Of2[w >> 1];
#pragma unroll
        for (int r = 0; r < 16; ++r) {
            const int d0 = (r & 3) + 8 * (r >> 2) + 4 * hi;
            dst[d0 * 32 + ql]        = accO0[r];
            dst[(d0 + 32) * 32 + ql] = accO1[r];
        }
    }
    __syncthreads();
    if (!(w & 1)) {
        const float* src = Of2[w >> 1];
#pragma unroll
        for (int r = 0; r < 16; ++r) {
            const int d0 = (r & 3) + 8 * (r >> 2) + 4 * hi;
            accO0[r] += src[d0 * 32 + ql];
            accO1[r] += src[(d0 + 32) * 32 + ql];
        }
    }
    __syncthreads();
    // stage B: wave 2 publishes; wave 0 accumulates
    if (w == 2) {
        float* dst = Of2[0];
#pragma unroll
        for (int r = 0; r < 16; ++r) {
            const int d0 = (r & 3) + 8 * (r >> 2) + 4 * hi;
            dst[d0 * 32 + ql]        = accO0[r];
            dst[(d0 + 32) * 32 + ql] = accO1[r];
        }
    }
    __syncthreads();
    unsigned* Ot = (unsigned*)&Of2[1][0];    // reuse 8KB as transpose buffer
    if (w == 0) {
        const float* src = Of2[0];
#pragma unroll
        for (int r = 0; r < 16; ++r) {
            const int d0 = (r & 3) + 8 * (r >> 2) + 4 * hi;
            accO0[r] += src[d0 * 32 + ql];
            accO1[r] += src[(d0 + 32) * 32 + ql];
        }
        const float invl = 1.f / lstar;
#pragma unroll
        for (int rq = 0; rq < 4; ++rq) {
            unsigned p0 = cvtpk(accO0[4*rq+0] * invl, accO0[4*rq+1] * invl);
            unsigned p1 = cvtpk(accO0[4*rq+2] * invl, accO0[4*rq+3] * invl);
            unsigned p2 = cvtpk(accO1[4*rq+0] * invl, accO1[4*rq+1] * invl);
            unsigned p3 = cvtpk(accO1[4*rq+2] * invl, accO1[4*rq+3] * invl);
            const int du0 = 4 * rq + 2 * hi;
            Ot[ql * 36 + du0]      = p0;
            Ot[ql * 36 + du0 + 1]  = p1;
            Ot[ql * 36 + du0 + 16] = p2;
            Ot[ql * 36 + du0 + 17] = p3;
        }
    }
    __syncthreads();
    {   // 256-thread coalesced store: q = tid>>3, d-group = tid&7 (8 d each)
        const int q = tid >> 3, dgrp = tid & 7;
        const int4 val = ((const int4*)(Ot + q * 36))[dgrp];
        *(int4*)(Ob + (size_t)(b * T_ + q0 + q) * D_ + h * 64 + dgrp * 8) = val;
    }
}

// ---------------------------------------------------------------------------
extern "C" void kernel_launch(void* const* d_in, const int* in_sizes, int n_in,
                              void* d_out, int out_size, void* d_ws, size_t ws_size,
                              hipStream_t stream)
{
    const float* x  = (const float*)d_in[0];
    const float* wq = (const float*)d_in[1];
    const float* wk = (const float*)d_in[2];
    const float* wv = (const float*)d_in[3];
    const float* wo = (const float*)d_in[4];
    float* out = (float*)d_out;

    const size_t NTOK = (size_t)TOK * D_;
    const size_t NW   = (size_t)D_ * D_;
    short* xb  = (short*)d_ws;
    short* wqb = xb  + NTOK;
    short* wkb = wqb + NW;
    short* wvb = wkb + NW;
    short* wob = wvb + NW;
    short* Qb  = wob + NW;
    short* Kb  = Qb  + NTOK;
    short* Vtr = Kb  + NTOK;     // [2048][2048]: row = b*1024 + h*64 + d
    short* Obf = Vtr + NTOK;
    float2* tab = (float2*)(Obf + NTOK);

    cast_table<<<4352, 256, 0, stream>>>(x, wq, wk, wv, wo,
                                         xb, wqb, wkb, wvb, wob, tab);

    gemm_abt_mfma<1><<<dim3(24, 32), 256, 0, stream>>>(
        xb, wqb, wkb, wvb, Qb, Kb, Vtr, nullptr, D_);

    rope_apply2<<<4096, 256, 0, stream>>>(Qb, Kb, tab);

    attn_v6<<<2048, 256, 0, stream>>>(Qb, Kb, Vtr, Obf);

    gemm_abt_mfma<0><<<dim3(8, 32), 256, 0, stream>>>(
        Obf, wob, wob, wob, nullptr, nullptr, nullptr, out, D_);
}

// Round 11
// 257.006 us; speedup vs baseline: 9.3691x; 9.3691x over previous
//
#include <hip/hip_runtime.h>
#include <hip/hip_bf16.h>
#include <math.h>

#define B_  2
#define T_  2048
#define D_  1024
#define H_  16
#define TOK (B_*T_)   // 4096

typedef __attribute__((ext_vector_type(8)))  short bf16x8;
typedef __attribute__((ext_vector_type(4)))  float f32x4;
typedef __attribute__((ext_vector_type(16))) float f32x16;

static __device__ __forceinline__ float bf2f(short u) {
    union { unsigned int i; float f; } c;
    c.i = ((unsigned int)(unsigned short)u) << 16;
    return c.f;
}
static __device__ __forceinline__ short f2bf(float f) {
    union { float f; unsigned int i; } c; c.f = f;
    unsigned int r = c.i + 0x7fff + ((c.i >> 16) & 1);   // RTNE
    return (short)(r >> 16);
}
// v_cvt_pk_bf16_f32: packs {lo, hi} into one u32 (no builtin on gfx950)
static __device__ __forceinline__ unsigned cvtpk(float lo, float hi2) {
    unsigned r;
    asm("v_cvt_pk_bf16_f32 %0, %1, %2" : "=v"(r) : "v"(lo), "v"(hi2));
    return r;
}

// ---------------------------------------------------------------------------
// fused f32->bf16 cast for x + 4 weights, plus RoPE cos/sin table.
// ---------------------------------------------------------------------------
__global__ __launch_bounds__(256) void cast_table(
    const float* __restrict__ x,  const float* __restrict__ wq,
    const float* __restrict__ wk, const float* __restrict__ wv,
    const float* __restrict__ wo,
    short* __restrict__ xb,  short* __restrict__ wqb,
    short* __restrict__ wkb, short* __restrict__ wvb,
    short* __restrict__ wob, float2* __restrict__ tab)
{
    const int bid = blockIdx.x;
    if (bid >= 4096) {                       // RoPE table: T_*32 entries
        int idx = (bid - 4096) * 256 + threadIdx.x;
        int t = idx >> 5, i = idx & 31;
        float freq = __powf(10000.f, -(float)i * (1.0f / 32.0f));
        float s, c;
        sincosf((float)t * freq, &s, &c);
        tab[idx] = make_float2(c, s);
        return;
    }
    int i = bid * 256 + threadIdx.x;         // 0 .. 1048575
    const float* src; short* dst; int off;
    if (i < 524288) { src = x; dst = xb; off = i; }
    else {
        int j = i - 524288;
        int wsel = j >> 17;  off = j & 131071;
        src = wsel == 0 ? wq : wsel == 1 ? wk : wsel == 2 ? wv : wo;
        dst = wsel == 0 ? wqb : wsel == 1 ? wkb : wsel == 2 ? wvb : wob;
    }
    const float4* p = reinterpret_cast<const float4*>(src);
    float4 a = p[2*off], b = p[2*off+1];
    bf16x8 o;
    o[0] = f2bf(a.x); o[1] = f2bf(a.y); o[2] = f2bf(a.z); o[3] = f2bf(a.w);
    o[4] = f2bf(b.x); o[5] = f2bf(b.y); o[6] = f2bf(b.z); o[7] = f2bf(b.w);
    reinterpret_cast<bf16x8*>(dst)[off] = o;
}

// ---------------------------------------------------------------------------
// Fused RoPE for Q and K.  Q pre-scaled by 0.125*log2(e)  (exp2-domain softmax).
// ---------------------------------------------------------------------------
__global__ __launch_bounds__(256) void rope_apply2(short* __restrict__ Q,
                                                   short* __restrict__ K,
                                                   const float2* __restrict__ tab)
{
    int g = blockIdx.x * 256 + threadIdx.x;
    short* X;
    float sc;
    int q;
    if (g < 524288) { X = Q; sc = 0.18033688011112042f; q = g; }
    else            { X = K; sc = 1.0f;                 q = g - 524288; }
    int p0 = q << 2;
    int tt = (p0 >> 9) & (T_ - 1);
    int i0 = p0 & 31;
    int4 v = reinterpret_cast<int4*>(X)[q];
    int out[4]; int vv[4] = {v.x, v.y, v.z, v.w};
#pragma unroll
    for (int j = 0; j < 4; ++j) {
        float2 cs = tab[tt * 32 + i0 + j];
        float re = bf2f((short)(vv[j] & 0xffff));
        float im = bf2f((short)(((unsigned int)vv[j]) >> 16));
        float nr = (re * cs.x - im * cs.y) * sc;
        float ni = (re * cs.y + im * cs.x) * sc;
        out[j] = (int)(unsigned short)f2bf(nr) |
                 ((int)(unsigned short)f2bf(ni) << 16);
    }
    reinterpret_cast<int4*>(X)[q] = make_int4(out[0], out[1], out[2], out[3]);
}

// ---------------------------------------------------------------------------
// bf16 MFMA GEMM (m97 structure).  sel==2 with BF16OUT writes V TRANSPOSED.
// ---------------------------------------------------------------------------
template<int BF16OUT>
__global__ __launch_bounds__(256) void gemm_abt_mfma(
    const short* __restrict__ A,
    const short* __restrict__ B0, const short* __restrict__ B1, const short* __restrict__ B2,
    short* __restrict__ Ob0, short* __restrict__ Ob1, short* __restrict__ Ob2,
    float* __restrict__ Of0, int K)
{
    __shared__ short As[128 * 32];
    __shared__ short Bs[128 * 32];
    __shared__ short Tb[128 * 136];          // transpose buffer (V path only)
    const int sel = blockIdx.x >> 3;
    const int bn  = (blockIdx.x & 7) << 7;
    const int bm  = blockIdx.y << 7;
    const short* Bm = sel == 0 ? B0 : (sel == 1 ? B1 : B2);
    short* Obp      = sel == 0 ? Ob0 : (sel == 1 ? Ob1 : Ob2);
    const int tid  = threadIdx.x;
    const int wv   = tid >> 6, lane = tid & 63;
    const int wr   = wv >> 1,  wc   = wv & 1;
    const int fr   = lane & 15, fg  = lane >> 4;
    const int srow  = lane >> 2;
    const int skoff = (lane & 3) << 3;
    f32x4 acc[4][4] = {};

    for (int k0 = 0; k0 < K; k0 += 32) {
        __syncthreads();
#pragma unroll
        for (int it = 0; it < 2; ++it) {
            const int c = wv * 2 + it;
            const int r = 16 * c + srow;
            __builtin_amdgcn_global_load_lds(
                (const __attribute__((address_space(1))) unsigned int*)
                    (A + (size_t)(bm + r) * K + k0 + skoff),
                (__attribute__((address_space(3))) unsigned int*)(As + c * 512),
                16, 0, 0);
            __builtin_amdgcn_global_load_lds(
                (const __attribute__((address_space(1))) unsigned int*)
                    (Bm + (size_t)(bn + r) * K + k0 + skoff),
                (__attribute__((address_space(3))) unsigned int*)(Bs + c * 512),
                16, 0, 0);
        }
        __syncthreads();
        bf16x8 af[4], bfr[4];
#pragma unroll
        for (int m = 0; m < 4; ++m)
            af[m] = *(const bf16x8*)(As + (wr * 64 + m * 16 + fr) * 32 + fg * 8);
#pragma unroll
        for (int n = 0; n < 4; ++n)
            bfr[n] = *(const bf16x8*)(Bs + (wc * 64 + n * 16 + fr) * 32 + fg * 8);
#pragma unroll
        for (int m = 0; m < 4; ++m)
#pragma unroll
            for (int n = 0; n < 4; ++n)
                acc[m][n] = __builtin_amdgcn_mfma_f32_16x16x32_bf16(
                                af[m], bfr[n], acc[m][n], 0, 0, 0);
    }

    if (BF16OUT && sel == 2) {
#pragma unroll
        for (int m = 0; m < 4; ++m)
#pragma unroll
            for (int n = 0; n < 4; ++n) {
                const int dl = wc * 64 + n * 16 + fr;
                const int tk = wr * 64 + m * 16 + fg * 4;
                unsigned lo  = cvtpk(acc[m][n][0], acc[m][n][1]);
                unsigned hi2 = cvtpk(acc[m][n][2], acc[m][n][3]);
                *(unsigned*)(Tb + dl * 136 + tk)     = lo;
                *(unsigned*)(Tb + dl * 136 + tk + 2) = hi2;
            }
        __syncthreads();
        const int bb = bm >> 11;
#pragma unroll
        for (int it = 0; it < 8; ++it) {
            const int c  = it * 256 + tid;
            const int dl = c >> 4;
            const int off = (c & 15) << 3;
            bf16x8 v = *(const bf16x8*)(Tb + dl * 136 + off);
            *(bf16x8*)(Obp + (size_t)(bb * 1024 + bn + dl) * 2048
                             + (bm & 2047) + off) = v;
        }
        return;
    }

    const int row0 = bm + wr * 64 + fg * 4;
    const int col0 = bn + wc * 64 + fr;
#pragma unroll
    for (int m = 0; m < 4; ++m)
#pragma unroll
        for (int n = 0; n < 4; ++n)
#pragma unroll
            for (int j = 0; j < 4; ++j) {
                const size_t idx = (size_t)(row0 + m * 16 + j) * 1024 + col0 + n * 16;
                if (BF16OUT) Obp[idx] = f2bf(acc[m][n][j]);
                else         Of0[idx] = acc[m][n][j];
            }
}

// ---------------------------------------------------------------------------
// Flash attention v6b: identical to v6 except __launch_bounds__(256, 4).
// R10 post-mortem: (256,8) forced a 64-VGPR budget -> compiler allocated 32
// and spilled both f32x16 accumulators to scratch (8.6 GB HBM traffic, 17x
// slowdown).  (256,4) gives a 128-VGPR budget: no spill (body needs ~70-90),
// 16 waves/CU resident (~50% occupancy) -- 4x v5's residency, same balanced
// work distribution (complementary rank pairs, 4-way kv-split + LDS combine).
// ---------------------------------------------------------------------------
__global__ __launch_bounds__(256, 4) void attn_v6(
    const short* __restrict__ Qb, const short* __restrict__ Kb,
    const short* __restrict__ Vt, short* __restrict__ Ob)
{
    __shared__ float Of2[2][2048];           // 16 KB combine buffers
    __shared__ float Ml[4][2][32];           // per-wave m,l

    const int tid  = threadIdx.x;
    const int w    = tid >> 6, lane = tid & 63;
    const int ql   = lane & 31, hi = lane >> 5;

    // balanced bid -> (bh, rank): each CU's round-robin set = complementary pairs
    const int bid = (int)blockIdx.x;         // 0..2047
    const int u  = bid >> 8;                 // 0..7
    const int v  = bid & 255;
    const int bh = v & 31;
    const int r0 = (v >> 5) & 7;
    const int rank = (u & 1) ? (63 - ((u >> 1) << 3) - r0)
                             : (((u >> 1) << 3) + r0);
    const int b   = bh >> 4, h = bh & 15;
    const int q0  = rank * 32;
    const int q_glob = q0 + ql;
    const int nt  = (rank >> 1) + 1;

    // Q fragments (B-operand): lane needs Q[q_glob][16*ds + 8*hi + e]
    const short* qp = Qb + (size_t)(b * T_ + q_glob) * D_ + h * 64 + hi * 8;
    bf16x8 qf[4];
#pragma unroll
    for (int ds = 0; ds < 4; ++ds)
        qf[ds] = *(const bf16x8*)(qp + 16 * ds);

    float m_run = -3e38f, l_run = 0.f;
    f32x16 accO0, accO1;
#pragma unroll
    for (int r = 0; r < 16; ++r) { accO0[r] = 0.f; accO1[r] = 0.f; }

    const short* kbase = Kb + (size_t)(b * T_) * D_ + h * 64 + hi * 8;
    const short* vbase = Vt + (size_t)(bh * 64) * 2048 + hi * 8;

    for (int t = w; t < nt; t += 4) {        // interleaved kv chunks
        const int K0 = t << 6;
        const bool diag  = (K0 + 63 > q0);
        const bool useHi = (K0 + 32 <= q0 + 31);

        // ---- K fragment loads (16B per lane) ----
        const short* kp = kbase + (size_t)K0 * D_;
        bf16x8 kf0[4], kf1[4];
#pragma unroll
        for (int ds = 0; ds < 4; ++ds)
            kf0[ds] = *(const bf16x8*)(kp + (size_t)ql * D_ + 16 * ds);
        if (useHi) {
#pragma unroll
            for (int ds = 0; ds < 4; ++ds)
                kf1[ds] = *(const bf16x8*)(kp + (size_t)(32 + ql) * D_ + 16 * ds);
        }

        // ---- S^T = K Q ----
        f32x16 s0, s1;
#pragma unroll
        for (int r = 0; r < 16; ++r) { s0[r] = 0.f; s1[r] = 0.f; }
#pragma unroll
        for (int ds = 0; ds < 4; ++ds)
            s0 = __builtin_amdgcn_mfma_f32_32x32x16_bf16(kf0[ds], qf[ds], s0, 0, 0, 0);
        if (useHi) {
#pragma unroll
            for (int ds = 0; ds < 4; ++ds)
                s1 = __builtin_amdgcn_mfma_f32_32x32x16_bf16(kf1[ds], qf[ds], s1, 0, 0, 0);
        }

        // ---- causal mask ----
        if (diag) {
            const int qrel = q_glob - K0;
#pragma unroll
            for (int r = 0; r < 16; ++r) {
                const int kv0 = 4 * hi + (r & 3) + 8 * (r >> 2);
                s0[r] = (kv0 <= qrel) ? s0[r] : -3e38f;
            }
            if (useHi) {
#pragma unroll
                for (int r = 0; r < 16; ++r) {
                    const int kv0 = 4 * hi + (r & 3) + 8 * (r >> 2);
                    s1[r] = (kv0 + 32 <= qrel) ? s1[r] : -3e38f;
                }
            }
        }

        // ---- online softmax (exp2 domain, defer-max) ----
        float mloc = s0[0];
#pragma unroll
        for (int r = 1; r < 16; ++r) mloc = fmaxf(mloc, s0[r]);
        if (useHi) {
#pragma unroll
            for (int r = 0; r < 16; ++r) mloc = fmaxf(mloc, s1[r]);
        }
        mloc = fmaxf(mloc, __shfl_xor(mloc, 32));
        if (!__all(mloc <= m_run + 11.5f)) {
            const float mnew = fmaxf(m_run, mloc);
            const float corr = exp2f(m_run - mnew);
            m_run = mnew;
            l_run *= corr;
#pragma unroll
            for (int r = 0; r < 16; ++r) { accO0[r] *= corr; accO1[r] *= corr; }
        }
        float lsum = 0.f;
#pragma unroll
        for (int r = 0; r < 16; ++r) { s0[r] = exp2f(s0[r] - m_run); lsum += s0[r]; }
        if (useHi) {
#pragma unroll
            for (int r = 0; r < 16; ++r) { s1[r] = exp2f(s1[r] - m_run); lsum += s1[r]; }
        }
        lsum += __shfl_xor(lsum, 32);
        l_run += lsum;

        // ---- pack P to bf16 ----
        unsigned W[8][2];
#pragma unroll
        for (int q4 = 0; q4 < 4; ++q4) {
            W[q4][0] = cvtpk(s0[4*q4+0], s0[4*q4+1]);
            W[q4][1] = cvtpk(s0[4*q4+2], s0[4*q4+3]);
        }
        if (useHi) {
#pragma unroll
            for (int q4 = 0; q4 < 4; ++q4) {
                W[q4 + 4][0] = cvtpk(s1[4*q4+0], s1[4*q4+1]);
                W[q4 + 4][1] = cvtpk(s1[4*q4+2], s1[4*q4+3]);
            }
        }

        // ---- PV: O^T += V^T P^T ----
#pragma unroll
        for (int sl = 0; sl < 4; ++sl) {
            if (sl < 2 || useHi) {
                const int qe = 2 * sl, qo = qe + 1;
                unsigned srcA = hi ? W[qe][0] : W[qo][0];
                unsigned srcB = hi ? W[qe][1] : W[qo][1];
                unsigned xA = (unsigned)__shfl_xor((int)srcA, 32);
                unsigned xB = (unsigned)__shfl_xor((int)srcB, 32);
                union { unsigned u[4]; bf16x8 v; } pu;
                pu.u[0] = hi ? xA : W[qe][0];
                pu.u[1] = hi ? xB : W[qe][1];
                pu.u[2] = hi ? W[qo][0] : xA;
                pu.u[3] = hi ? W[qo][1] : xB;
                bf16x8 vf0 = *(const bf16x8*)(vbase + (size_t)ql * 2048        + K0 + 16 * sl);
                bf16x8 vf1 = *(const bf16x8*)(vbase + (size_t)(32 + ql) * 2048 + K0 + 16 * sl);
                accO0 = __builtin_amdgcn_mfma_f32_32x32x16_bf16(vf0, pu.v, accO0, 0, 0, 0);
                accO1 = __builtin_amdgcn_mfma_f32_32x32x16_bf16(vf1, pu.v, accO1, 0, 0, 0);
            }
        }
    }

    // ================= cross-wave combine =================
    if (hi == 0) { Ml[w][0][ql] = m_run; Ml[w][1][ql] = l_run; }
    __syncthreads();
    const float mstar = fmaxf(fmaxf(Ml[0][0][ql], Ml[1][0][ql]),
                              fmaxf(Ml[2][0][ql], Ml[3][0][ql]));
    const float lstar = exp2f(Ml[0][0][ql] - mstar) * Ml[0][1][ql]
                      + exp2f(Ml[1][0][ql] - mstar) * Ml[1][1][ql]
                      + exp2f(Ml[2][0][ql] - mstar) * Ml[2][1][ql]
                      + exp2f(Ml[3][0][ql] - mstar) * Ml[3][1][ql];
    {
        const float wgt = exp2f(m_run - mstar);   // 0 for empty chunks
#pragma unroll
        for (int r = 0; r < 16; ++r) { accO0[r] *= wgt; accO1[r] *= wgt; }
    }
    // stage A: waves 1,3 publish; waves 0,2 accumulate
    if (w & 1) {
        float* dst = Of2[w >> 1];
#pragma unroll
        for (int r = 0; r < 16; ++r) {
            const int d0 = (r & 3) + 8 * (r >> 2) + 4 * hi;
            dst[d0 * 32 + ql]        = accO0[r];
            dst[(d0 + 32) * 32 + ql] = accO1[r];
        }
    }
    __syncthreads();
    if (!(w & 1)) {
        const float* src = Of2[w >> 1];
#pragma unroll
        for (int r = 0; r < 16; ++r) {
            const int d0 = (r & 3) + 8 * (r >> 2) + 4 * hi;
            accO0[r] += src[d0 * 32 + ql];
            accO1[r] += src[(d0 + 32) * 32 + ql];
        }
    }
    __syncthreads();
    // stage B: wave 2 publishes; wave 0 accumulates
    if (w == 2) {
        float* dst = Of2[0];
#pragma unroll
        for (int r = 0; r < 16; ++r) {
            const int d0 = (r & 3) + 8 * (r >> 2) + 4 * hi;
            dst[d0 * 32 + ql]        = accO0[r];
            dst[(d0 + 32) * 32 + ql] = accO1[r];
        }
    }
    __syncthreads();
    unsigned* Ot = (unsigned*)&Of2[1][0];    // reuse 8KB as transpose buffer
    if (w == 0) {
        const float* src = Of2[0];
#pragma unroll
        for (int r = 0; r < 16; ++r) {
            const int d0 = (r & 3) + 8 * (r >> 2) + 4 * hi;
            accO0[r] += src[d0 * 32 + ql];
            accO1[r] += src[(d0 + 32) * 32 + ql];
        }
        const float invl = 1.f / lstar;
#pragma unroll
        for (int rq = 0; rq < 4; ++rq) {
            unsigned p0 = cvtpk(accO0[4*rq+0] * invl, accO0[4*rq+1] * invl);
            unsigned p1 = cvtpk(accO0[4*rq+2] * invl, accO0[4*rq+3] * invl);
            unsigned p2 = cvtpk(accO1[4*rq+0] * invl, accO1[4*rq+1] * invl);
            unsigned p3 = cvtpk(accO1[4*rq+2] * invl, accO1[4*rq+3] * invl);
            const int du0 = 4 * rq + 2 * hi;
            Ot[ql * 36 + du0]      = p0;
            Ot[ql * 36 + du0 + 1]  = p1;
            Ot[ql * 36 + du0 + 16] = p2;
            Ot[ql * 36 + du0 + 17] = p3;
        }
    }
    __syncthreads();
    {   // 256-thread coalesced store: q = tid>>3, d-group = tid&7 (8 d each)
        const int q = tid >> 3, dgrp = tid & 7;
        const int4 val = ((const int4*)(Ot + q * 36))[dgrp];
        *(int4*)(Ob + (size_t)(b * T_ + q0 + q) * D_ + h * 64 + dgrp * 8) = val;
    }
}

// ---------------------------------------------------------------------------
extern "C" void kernel_launch(void* const* d_in, const int* in_sizes, int n_in,
                              void* d_out, int out_size, void* d_ws, size_t ws_size,
                              hipStream_t stream)
{
    const float* x  = (const float*)d_in[0];
    const float* wq = (const float*)d_in[1];
    const float* wk = (const float*)d_in[2];
    const float* wv = (const float*)d_in[3];
    const float* wo = (const float*)d_in[4];
    float* out = (float*)d_out;

    const size_t NTOK = (size_t)TOK * D_;
    const size_t NW   = (size_t)D_ * D_;
    short* xb  = (short*)d_ws;
    short* wqb = xb  + NTOK;
    short* wkb = wqb + NW;
    short* wvb = wkb + NW;
    short* wob = wvb + NW;
    short* Qb  = wob + NW;
    short* Kb  = Qb  + NTOK;
    short* Vtr = Kb  + NTOK;     // [2048][2048]: row = b*1024 + h*64 + d
    short* Obf = Vtr + NTOK;
    float2* tab = (float2*)(Obf + NTOK);

    cast_table<<<4352, 256, 0, stream>>>(x, wq, wk, wv, wo,
                                         xb, wqb, wkb, wvb, wob, tab);

    gemm_abt_mfma<1><<<dim3(24, 32), 256, 0, stream>>>(
        xb, wqb, wkb, wvb, Qb, Kb, Vtr, nullptr, D_);

    rope_apply2<<<4096, 256, 0, stream>>>(Qb, Kb, tab);

    attn_v6<<<2048, 256, 0, stream>>>(Qb, Kb, Vtr, Obf);

    gemm_abt_mfma<0><<<dim3(8, 32), 256, 0, stream>>>(
        Obf, wob, wob, wob, nullptr, nullptr, nullptr, out, D_);
}